// Round 15
// baseline (27.837 us; speedup 1.0000x reference)
//
#include <hip/hip_runtime.h>

#define NQ 11
#define NC 3
#define NANG (NC * 66)
#define BLOCK 128

typedef float f2 __attribute__((ext_vector_type(2)));

__device__ __forceinline__ f2 swp(f2 v) { return __builtin_shufflevector(v, v, 1, 0); }

// DPP quad_perm: 0xB1 = xor1, 0x4E = xor2
template<int CTRL>
__device__ __forceinline__ float dppx(float v) {
  return __int_as_float(__builtin_amdgcn_update_dpp(
      0, __float_as_int(v), CTRL, 0xF, 0xF, false));
}
template<int CTRL>
__device__ __forceinline__ f2 dpp2(f2 v) {
  f2 r; r.x = dppx<CTRL>(v.x); r.y = dppx<CTRL>(v.y); return r;
}
// ds_swizzle BitMode xor patterns: xor4 = 0x101F, xor8 = 0x201F
template<int OFF>
__device__ __forceinline__ float swz1(float v) {
  return __int_as_float(__builtin_amdgcn_ds_swizzle(__float_as_int(v), OFF));
}
template<int OFF>
__device__ __forceinline__ f2 swz2(f2 v) {
  f2 r; r.x = swz1<OFF>(v.x); r.y = swz1<OFF>(v.y); return r;
}
// gfx950 permlane swaps (VALU pipe)
__device__ __forceinline__ float plp16(float v, int lane) {
  auto r = __builtin_amdgcn_permlane16_swap(__float_as_int(v), __float_as_int(v), false, false);
  return __int_as_float((lane & 16) ? r[0] : r[1]);
}
__device__ __forceinline__ float plp32(float v, int lane) {
  auto r = __builtin_amdgcn_permlane32_swap(__float_as_int(v), __float_as_int(v), false, false);
  return __int_as_float((lane & 32) ? r[0] : r[1]);
}
__device__ __forceinline__ f2 plp16_2(f2 v, int lane) {
  f2 r; r.x = plp16(v.x, lane); r.y = plp16(v.y, lane); return r;
}
__device__ __forceinline__ f2 plp32_2(f2 v, int lane) {
  f2 r; r.x = plp32(v.x, lane); r.y = plp32(v.y, lane); return r;
}
__device__ __forceinline__ float plsum16(float v) {
  auto r = __builtin_amdgcn_permlane16_swap(__float_as_int(v), __float_as_int(v), false, false);
  return __int_as_float(r[0]) + __int_as_float(r[1]);
}
__device__ __forceinline__ float plsum32(float v) {
  auto r = __builtin_amdgcn_permlane32_swap(__float_as_int(v), __float_as_int(v), false, false);
  return __int_as_float(r[0]) + __int_as_float(r[1]);
}

// SU(2) U = [[a,b],[-conj(b),conj(a)]] as float4 (ar,ai,br,bi).
// In-thread pair apply: (v0,v1) <- U (v0,v1)
__device__ __forceinline__ void apply2p(f2& v0, f2& v1, float4 U) {
  const f2 ai2 = {-U.y, U.y};
  const f2 bi2 = {-U.w, U.w};
  const f2 w0 = swp(v0), w1 = swp(v1);
  const f2 n0 =  U.x * v0 + ai2 * w0 + U.z * v1 + bi2 * w1;
  const f2 n1 = -U.z * v0 + bi2 * w0 + U.x * v1 - ai2 * w1;
  v0 = n0; v1 = n1;
}
// own/partner row apply: v <- row(hi) of U applied to (own=v, partner=p)
__device__ __forceinline__ void gpartp(f2& v, f2 p, float4 U, bool hi) {
  const f2 ai2 = hi ? f2{U.y, -U.y} : f2{-U.y, U.y};
  const float br = hi ? -U.z : U.z;
  const f2 bi2 = {-U.w, U.w};
  v = U.x * v + ai2 * swp(v) + br * p + bi2 * swp(p);
}
// SU2 product A*B (B applied first)
__device__ __forceinline__ float4 su2mul(float4 A, float4 B) {
  return make_float4(
    (A.x*B.x - A.y*B.y) - (A.z*B.z + A.w*B.w),
    (A.x*B.y + A.y*B.x) - (A.w*B.z - A.z*B.w),
    (A.x*B.z - A.y*B.w) + (A.z*B.x + A.w*B.y),
    (A.x*B.w + A.y*B.z) + (A.w*B.x - A.z*B.y));
}
// wave-bit gate (q4): 16 amps, 2 waves, float4-packed exchange
__device__ __forceinline__ void g_wave16(f2 (&s)[16], float4 U, float4* buf, int wave, int lane) {
  const int base = (wave << 6) | lane;   // 0..127
#pragma unroll
  for (int i = 0; i < 8; ++i)
    buf[(i << 7) | base] = make_float4(s[2*i].x, s[2*i].y, s[2*i+1].x, s[2*i+1].y);
  __syncthreads();
  const int pbase = ((wave ^ 1) << 6) | lane;
  const bool hi = (wave & 1) != 0;
#pragma unroll
  for (int i = 0; i < 8; ++i) {
    const float4 p = buf[(i << 7) | pbase];
    gpartp(s[2*i],   f2{p.x, p.y}, U, hi);
    gpartp(s[2*i+1], f2{p.z, p.w}, U, hi);
  }
}

__global__ __launch_bounds__(BLOCK) void qsim_kernel(
    const float* __restrict__ x, const float* __restrict__ W,
    const float* __restrict__ bias, float* __restrict__ out) {
  const int bidx = blockIdx.x;
  const int tid = threadIdx.x;
  const int lane = tid & 63, wave = tid >> 6;   // wave 0..1

  __shared__ float xs[NQ];
  __shared__ float ang[NANG];
  __shared__ float4 m1s[NC * NQ];   // fused 1q matrices (SU2)
  __shared__ float4 m2s[NC * NQ];   // fused controlled matrices (SU2)
  __shared__ float4 v1s[NC * 10];   // V[t] = m2[t-1] * m1[t], t=1..10
  __shared__ float4 js[2];          // J[c] = m1[c+1][0] * m2[c][10]
  __shared__ float4 ex0[1024];
  __shared__ float4 ex1[1024];
  __shared__ float red[2][24];

  if (tid < NQ) xs[tid] = x[bidx * NQ + tid];
  __syncthreads();

#pragma unroll
  for (int r2 = 0; r2 < 2; ++r2) {
    const int id = tid + 128 * r2;
    if (id < NANG) {
      const int c = id / 66, o = id - c * 66;
      const float* wr = W + (c * 66 + o) * NQ;
      float s = bias[c * 66 + o];
#pragma unroll
      for (int i = 0; i < NQ; ++i) s += wr[i] * xs[i];
      ang[id] = s;
    }
  }
  __syncthreads();

  if (tid < 2 * NC * NQ) {
    const int kind = tid / (NC * NQ);
    const int id = tid - kind * (NC * NQ);
    const int c = id / NQ, q = id - c * NQ;
    const float* a = ang + c * 66;
    if (kind == 0) {
      // U = RZ(a3) RY(a2) RZ(a1) RY(a0), SU2 form (a,b)
      float s0,c0,s1,c1,s2,c2,s3,c3;
      sincosf(0.5f*a[q],      &s0,&c0);
      sincosf(0.5f*a[11+q],   &s1,&c1);
      sincosf(0.5f*a[22+q],   &s2,&c2);
      sincosf(0.5f*a[33+q],   &s3,&c3);
      const float mar = c1*c0, mai = -s1*c0;
      const float mbr = -c1*s0, mbi = s1*s0;
      const float nar = c2*mar + s2*mbr, nai = c2*mai - s2*mbi;
      const float nbr = c2*mbr - s2*mar, nbi = c2*mbi + s2*mai;
      m1s[id] = make_float4(c3*nar + s3*nai, c3*nai - s3*nar,
                            c3*nbr + s3*nbi, c3*nbi - s3*nbr);
    } else {
      // U = RZ(a5) RY(a4)
      float s4,c4,s5,c5;
      sincosf(0.5f*a[44+q], &s4,&c4);
      sincosf(0.5f*a[55+q], &s5,&c5);
      m2s[id] = make_float4(c5*c4, -s5*c4, -c5*s4, s5*s4);
    }
  }
  __syncthreads();

  // V[c][t] = m2[c][t-1] * m1[c][t]; J[c] = m1[c+1][0] * m2[c][10]
  if (tid < NC * 10) {
    const int c = tid / 10, tt = tid - c * 10, t = tt + 1;
    v1s[tid] = su2mul(m2s[c*NQ + t - 1], m1s[c*NQ + t]);
  } else if (tid < NC * 10 + 2) {
    const int cc = tid - NC * 10;   // 0,1
    js[cc] = su2mul(m1s[(cc + 1) * NQ], m2s[cc * NQ + 10]);
  }
  __syncthreads();

  // amp bits: [3:0]=reg (b0<->q0, b1<->q8, b2<->q9, b3<->q10);
  // [9:4]=lane b0..b5 <-> q7,q6,q5,q3,q2,q1 ; [10]=wave bit <-> q4
  f2 s[16];
#pragma unroll
  for (int i = 0; i < 16; ++i) s[i] = f2{0.f, 0.f};
  if (tid == 0) s[0].x = 1.f;

  for (int c = 0; c < NC; ++c) {
    const float4* M1 = &m1s[c * NQ];
    const float4* VF = &v1s[c * 10];
    if (c == 0) { // e0: 1q(q0), reg b0 static (junction handles c=1,2)
      const float4 U = M1[0];
#pragma unroll
      for (int r = 0; r < 16; r += 2) apply2p(s[r], s[r + 1], U);
    }
    { // e1: F(1|0): target q1 (lane b5, permlane32), ctrl q0 = reg b0 (per-amp U)
      const bool hi = (lane & 32) != 0;
      const float4 U0 = M1[1], U1 = VF[0];
#pragma unroll
      for (int r = 0; r < 16; ++r)
        gpartp(s[r], plp32_2(s[r], lane), (r & 1) ? U1 : U0, hi);
    }
    { // e2: F(2|1): target q2 (lane b4, permlane16), ctrl q1 (lane b5)
      const float4 U = *((lane & 32) ? &VF[1] : &M1[2]);
      const bool hi = (lane & 16) != 0;
#pragma unroll
      for (int r = 0; r < 16; ++r) gpartp(s[r], plp16_2(s[r], lane), U, hi);
    }
    { // e3: F(3|2): target q3 (lane b3, xor8), ctrl q2 (lane b4)
      const float4 U = *((lane & 16) ? &VF[2] : &M1[3]);
      const bool hi = (lane & 8) != 0;
#pragma unroll
      for (int r = 0; r < 16; ++r) gpartp(s[r], swz2<0x201F>(s[r]), U, hi);
    }
    // e4: F(4|3): target q4 (wave bit), ctrl q3 (lane b3) — the ONE exchange
    g_wave16(s, *((lane & 8) ? &VF[3] : &M1[4]), (c & 1) ? ex1 : ex0, wave, lane);
    { // e5: F(5|4): target q5 (lane b2, xor4), ctrl q4 (wave bit)
      const float4 U = *((wave & 1) ? &VF[4] : &M1[5]);
      const bool hi = (lane & 4) != 0;
#pragma unroll
      for (int r = 0; r < 16; ++r) gpartp(s[r], swz2<0x101F>(s[r]), U, hi);
    }
    { // e6: F(6|5): target q6 (lane b1, dpp xor2), ctrl q5 (lane b2)
      const float4 U = *((lane & 4) ? &VF[5] : &M1[6]);
      const bool hi = (lane & 2) != 0;
#pragma unroll
      for (int r = 0; r < 16; ++r) gpartp(s[r], dpp2<0x4E>(s[r]), U, hi);
    }
    { // e7: F(7|6): target q7 (lane b0, dpp xor1), ctrl q6 (lane b1)
      const float4 U = *((lane & 2) ? &VF[6] : &M1[7]);
      const bool hi = (lane & 1) != 0;
#pragma unroll
      for (int r = 0; r < 16; ++r) gpartp(s[r], dpp2<0xB1>(s[r]), U, hi);
    }
    { // e8: F(8|7): target q8 = reg b1, ctrl q7 = lane b0 (per-lane U)
      const float4 U = *((lane & 1) ? &VF[7] : &M1[8]);
      apply2p(s[0], s[2], U);  apply2p(s[1], s[3], U);
      apply2p(s[4], s[6], U);  apply2p(s[5], s[7], U);
      apply2p(s[8], s[10], U); apply2p(s[9], s[11], U);
      apply2p(s[12], s[14], U); apply2p(s[13], s[15], U);
    }
    { // e9: F(9|8): target q9 = reg b2, ctrl q8 = reg b1 (static)
      const float4 U0 = M1[9], U1 = VF[8];
      apply2p(s[0], s[4], U0);  apply2p(s[1], s[5], U0);
      apply2p(s[2], s[6], U1);  apply2p(s[3], s[7], U1);
      apply2p(s[8], s[12], U0); apply2p(s[9], s[13], U0);
      apply2p(s[10], s[14], U1); apply2p(s[11], s[15], U1);
    }
    { // e10: F(10|9): target q10 = reg b3, ctrl q9 = reg b2 (static)
      const float4 U0 = M1[10], U1 = VF[9];
      apply2p(s[0], s[8], U0);  apply2p(s[1], s[9], U0);
      apply2p(s[2], s[10], U0); apply2p(s[3], s[11], U0);
      apply2p(s[4], s[12], U1); apply2p(s[5], s[13], U1);
      apply2p(s[6], s[14], U1); apply2p(s[7], s[15], U1);
    }
    if (c < 2) { // junction: 1q(q0)_{c+1} ∘ C(10->0)_c : target reg b0, U by reg b3
      const float4 Un = m1s[(c + 1) * NQ];
      const float4 Uj = js[c];
#pragma unroll
      for (int r = 0; r < 16; r += 2) apply2p(s[r], s[r + 1], (r & 8) ? Uj : Un);
    } else {     // e11: C(10->0): ctrl reg b3, target reg b0 (static)
      const float4 U = m2s[c * NQ + 10];
#pragma unroll
      for (int r = 8; r < 16; r += 2) apply2p(s[r], s[r + 1], U);
    }
  }

  // ---- expectations ----
  // X q4 via exchange through ex1 (safe: c=2 used ex0; its barrier retired ex1 reads)
  const int base = (wave << 6) | lane;
#pragma unroll
  for (int i = 0; i < 8; ++i)
    ex1[(i << 7) | base] = make_float4(s[2*i].x, s[2*i].y, s[2*i+1].x, s[2*i+1].y);
  __syncthreads();
  const int pbase = ((wave ^ 1) << 6) | lane;
  f2 aq4 = {0,0};
#pragma unroll
  for (int i = 0; i < 8; ++i) {
    const float4 p = ex1[(i << 7) | pbase];
    aq4 += s[2*i] * f2{p.x, p.y} + s[2*i+1] * f2{p.z, p.w};
  }

  f2 zt = {0,0}, z0v = {0,0}, z8v = {0,0}, z9v = {0,0}, z10v = {0,0};
#pragma unroll
  for (int r = 0; r < 16; ++r) {
    const f2 m = s[r] * s[r];
    zt += m;
    z0v  += (r & 1) ? -m : m;
    z8v  += (r & 2) ? -m : m;
    z9v  += (r & 4) ? -m : m;
    z10v += (r & 8) ? -m : m;
  }
  f2 aq0 = {0,0}, aq8 = {0,0}, aq9 = {0,0}, aq10 = {0,0};
#pragma unroll
  for (int r = 0; r < 16; ++r) {
    aq0  += s[r] * s[r ^ 1];
    aq8  += s[r] * s[r ^ 2];
    aq9  += s[r] * s[r ^ 4];
    aq10 += s[r] * s[r ^ 8];
  }
  f2 aq1={0,0}, aq2={0,0}, aq3={0,0}, aq5={0,0}, aq6={0,0}, aq7={0,0};
#pragma unroll
  for (int r = 0; r < 16; ++r) {
    aq1 += s[r] * plp32_2(s[r], lane);
    aq2 += s[r] * plp16_2(s[r], lane);
    aq3 += s[r] * swz2<0x201F>(s[r]);
    aq5 += s[r] * swz2<0x101F>(s[r]);
    aq6 += s[r] * dpp2<0x4E>(s[r]);
    aq7 += s[r] * dpp2<0xB1>(s[r]);
  }
  const float ztot = zt.x + zt.y;

  float v[22];
  v[0]=aq0.x+aq0.y; v[1]=aq1.x+aq1.y; v[2]=aq2.x+aq2.y; v[3]=aq3.x+aq3.y;
  v[4]=aq4.x+aq4.y; v[5]=aq5.x+aq5.y; v[6]=aq6.x+aq6.y;
  v[7]=aq7.x+aq7.y; v[8]=aq8.x+aq8.y; v[9]=aq9.x+aq9.y; v[10]=aq10.x+aq10.y;
  v[11] = z0v.x + z0v.y;                // Z q0
  v[12] = (lane & 32) ? -ztot : ztot;   // Z q1
  v[13] = (lane & 16) ? -ztot : ztot;   // Z q2
  v[14] = (lane & 8)  ? -ztot : ztot;   // Z q3
  v[15] = (wave & 1)  ? -ztot : ztot;   // Z q4
  v[16] = (lane & 4)  ? -ztot : ztot;   // Z q5
  v[17] = (lane & 2)  ? -ztot : ztot;   // Z q6
  v[18] = (lane & 1)  ? -ztot : ztot;   // Z q7
  v[19] = z8v.x + z8v.y;                // Z q8
  v[20] = z9v.x + z9v.y;                // Z q9
  v[21] = z10v.x + z10v.y;              // Z q10

  // reduction: DPP quad levels, pack 4/reg, ds_swizzle xor4/8, permlane 16/32
#pragma unroll
  for (int k = 0; k < 22; ++k) {
    v[k] += dppx<0xB1>(v[k]);
    v[k] += dppx<0x4E>(v[k]);
  }
  const int q4l = lane & 3;
  float wv[6];
#pragma unroll
  for (int p = 0; p < 5; ++p)
    wv[p] = q4l == 0 ? v[4*p] : (q4l == 1 ? v[4*p+1] : (q4l == 2 ? v[4*p+2] : v[4*p+3]));
  wv[5] = q4l == 0 ? v[20] : (q4l == 1 ? v[21] : 0.f);
#pragma unroll
  for (int p = 0; p < 6; ++p) {
    wv[p] += swz1<0x101F>(wv[p]);
    wv[p] += swz1<0x201F>(wv[p]);
    wv[p] = plsum16(wv[p]);
    wv[p] = plsum32(wv[p]);
  }
  if (lane < 4) {
#pragma unroll
    for (int p = 0; p < 6; ++p) red[wave][4*p + lane] = wv[p];
  }
  __syncthreads();
  if (tid < 22) {
    out[bidx * 22 + tid] = red[0][tid] + red[1][tid];
  }
}

extern "C" void kernel_launch(void* const* d_in, const int* in_sizes, int n_in,
                              void* d_out, int out_size, void* d_ws, size_t ws_size,
                              hipStream_t stream) {
  (void)n_in; (void)d_ws; (void)ws_size; (void)out_size;
  const float* x = (const float*)d_in[0];
  const float* W = (const float*)d_in[1];
  const float* b = (const float*)d_in[2];
  float* out = (float*)d_out;
  const int batch = in_sizes[0] / NQ;
  qsim_kernel<<<batch, BLOCK, 0, stream>>>(x, W, b, out);
}

// Round 16
// 20.415 us; speedup vs baseline: 1.3635x; 1.3635x over previous
//
#include <hip/hip_runtime.h>

#define NQ 11
#define NC 3
#define NANG (NC * 66)
#define BLOCK 256

typedef float f2 __attribute__((ext_vector_type(2)));

__device__ __forceinline__ f2 swp(f2 v) { return __builtin_shufflevector(v, v, 1, 0); }

// DPP quad_perm: 0xB1 = xor1, 0x4E = xor2
template<int CTRL>
__device__ __forceinline__ float dppx(float v) {
  return __int_as_float(__builtin_amdgcn_update_dpp(
      0, __float_as_int(v), CTRL, 0xF, 0xF, false));
}
template<int CTRL>
__device__ __forceinline__ f2 dpp2(f2 v) {
  f2 r; r.x = dppx<CTRL>(v.x); r.y = dppx<CTRL>(v.y); return r;
}
// ds_swizzle BitMode xor patterns: xor4 = 0x101F, xor8 = 0x201F
template<int OFF>
__device__ __forceinline__ float swz1(float v) {
  return __int_as_float(__builtin_amdgcn_ds_swizzle(__float_as_int(v), OFF));
}
template<int OFF>
__device__ __forceinline__ f2 swz2(f2 v) {
  f2 r; r.x = swz1<OFF>(v.x); r.y = swz1<OFF>(v.y); return r;
}
// gfx950 permlane swaps (VALU pipe)
__device__ __forceinline__ float plp16(float v, int lane) {
  auto r = __builtin_amdgcn_permlane16_swap(__float_as_int(v), __float_as_int(v), false, false);
  return __int_as_float((lane & 16) ? r[0] : r[1]);
}
__device__ __forceinline__ float plp32(float v, int lane) {
  auto r = __builtin_amdgcn_permlane32_swap(__float_as_int(v), __float_as_int(v), false, false);
  return __int_as_float((lane & 32) ? r[0] : r[1]);
}
__device__ __forceinline__ f2 plp16_2(f2 v, int lane) {
  f2 r; r.x = plp16(v.x, lane); r.y = plp16(v.y, lane); return r;
}
__device__ __forceinline__ f2 plp32_2(f2 v, int lane) {
  f2 r; r.x = plp32(v.x, lane); r.y = plp32(v.y, lane); return r;
}
__device__ __forceinline__ float plsum16(float v) {
  auto r = __builtin_amdgcn_permlane16_swap(__float_as_int(v), __float_as_int(v), false, false);
  return __int_as_float(r[0]) + __int_as_float(r[1]);
}
__device__ __forceinline__ float plsum32(float v) {
  auto r = __builtin_amdgcn_permlane32_swap(__float_as_int(v), __float_as_int(v), false, false);
  return __int_as_float(r[0]) + __int_as_float(r[1]);
}

// SU(2) U = [[a,b],[-conj(b),conj(a)]] as float4 (ar,ai,br,bi).
// In-thread pair apply: (v0,v1) <- U (v0,v1)
__device__ __forceinline__ void apply2p(f2& v0, f2& v1, float4 U) {
  const f2 ai2 = {-U.y, U.y};
  const f2 bi2 = {-U.w, U.w};
  const f2 w0 = swp(v0), w1 = swp(v1);
  const f2 n0 =  U.x * v0 + ai2 * w0 + U.z * v1 + bi2 * w1;
  const f2 n1 = -U.z * v0 + bi2 * w0 + U.x * v1 - ai2 * w1;
  v0 = n0; v1 = n1;
}
// own/partner row apply: v <- row(hi) of U applied to (own=v, partner=p)
__device__ __forceinline__ void gpartp(f2& v, f2 p, float4 U, bool hi) {
  const f2 ai2 = hi ? f2{U.y, -U.y} : f2{-U.y, U.y};
  const float br = hi ? -U.z : U.z;
  const f2 bi2 = {-U.w, U.w};
  v = U.x * v + ai2 * swp(v) + br * p + bi2 * swp(p);
}
// SU2 product A*B (B applied first)
__device__ __forceinline__ float4 su2mul(float4 A, float4 B) {
  return make_float4(
    (A.x*B.x - A.y*B.y) - (A.z*B.z + A.w*B.w),
    (A.x*B.y + A.y*B.x) - (A.w*B.z - A.z*B.w),
    (A.x*B.z - A.y*B.w) + (A.z*B.x + A.w*B.y),
    (A.x*B.w + A.y*B.z) + (A.w*B.x - A.z*B.y));
}
// wave-bit gate via LDS exchange (8 f2 per thread, 4 waves)
template<int WVX>
__device__ __forceinline__ void g_wave8(f2 (&s)[8], float4 U, f2* buf, int wave, int lane) {
  const int base = (wave << 6) | lane;
#pragma unroll
  for (int i = 0; i < 8; ++i) buf[(i << 8) | base] = s[i];
  __syncthreads();
  const int pbase = ((wave ^ WVX) << 6) | lane;
  const bool hi = (wave & WVX) != 0;
#pragma unroll
  for (int i = 0; i < 8; ++i) gpartp(s[i], buf[(i << 8) | pbase], U, hi);
}

__global__ __launch_bounds__(BLOCK) void qsim_kernel(
    const float* __restrict__ x, const float* __restrict__ W,
    const float* __restrict__ bias, float* __restrict__ out) {
  const int bidx = blockIdx.x;
  const int tid = threadIdx.x;
  const int lane = tid & 63, wave = tid >> 6;   // wave 0..3

  __shared__ float xs[NQ];
  __shared__ float ang[NANG];
  __shared__ float4 m1s[NC * NQ];   // fused 1q matrices (SU2)
  __shared__ float4 m2s[NC * NQ];   // fused controlled matrices (SU2)
  __shared__ float4 v1s[NC * 10];   // V[t] = m2[t-1] * m1[t], t=1..10
  __shared__ float4 js[2];          // J[c] = m1[c+1][0] * m2[c][10]
  __shared__ f2 ex0[2048];
  __shared__ f2 ex1[2048];
  __shared__ float red[4][24];

  if (tid < NQ) xs[tid] = x[bidx * NQ + tid];
  __syncthreads();

  if (tid < NANG) {
    const int c = tid / 66, o = tid - c * 66;
    const float* wr = W + (c * 66 + o) * NQ;
    float s = bias[c * 66 + o];
#pragma unroll
    for (int i = 0; i < NQ; ++i) s += wr[i] * xs[i];
    ang[tid] = s;
  }
  __syncthreads();

  if (tid < 2 * NC * NQ) {
    const int kind = tid / (NC * NQ);
    const int id = tid - kind * (NC * NQ);
    const int c = id / NQ, q = id - c * NQ;
    const float* a = ang + c * 66;
    if (kind == 0) {
      // U = RZ(a3) RY(a2) RZ(a1) RY(a0), SU2 form (a,b)
      float s0,c0,s1,c1,s2,c2,s3,c3;
      sincosf(0.5f*a[q],      &s0,&c0);
      sincosf(0.5f*a[11+q],   &s1,&c1);
      sincosf(0.5f*a[22+q],   &s2,&c2);
      sincosf(0.5f*a[33+q],   &s3,&c3);
      const float mar = c1*c0, mai = -s1*c0;
      const float mbr = -c1*s0, mbi = s1*s0;
      const float nar = c2*mar + s2*mbr, nai = c2*mai - s2*mbi;
      const float nbr = c2*mbr - s2*mar, nbi = c2*mbi + s2*mai;
      m1s[id] = make_float4(c3*nar + s3*nai, c3*nai - s3*nar,
                            c3*nbr + s3*nbi, c3*nbi - s3*nbr);
    } else {
      // U = RZ(a5) RY(a4)
      float s4,c4,s5,c5;
      sincosf(0.5f*a[44+q], &s4,&c4);
      sincosf(0.5f*a[55+q], &s5,&c5);
      m2s[id] = make_float4(c5*c4, -s5*c4, -c5*s4, s5*s4);
    }
  }
  __syncthreads();

  // V[c][t] = m2[c][t-1] * m1[c][t]; J[c] = m1[c+1][0] * m2[c][10]
  if (tid < NC * 10) {
    const int c = tid / 10, tt = tid - c * 10, t = tt + 1;
    v1s[tid] = su2mul(m2s[c*NQ + t - 1], m1s[c*NQ + t]);
  } else if (tid < NC * 10 + 2) {
    const int cc = tid - NC * 10;   // 0,1
    js[cc] = su2mul(m1s[(cc + 1) * NQ], m2s[cc * NQ + 10]);
  }
  __syncthreads();

  // amp bits: [2:0]=reg (b0<->q0, b1<->q9, b2<->q10);
  // [8:3]=lane bits 0..5 <-> q8,q7,q4,q3,q2,q1 ; [10:9]=wave bits 0..1 <-> q6,q5
  f2 s[8];
#pragma unroll
  for (int i = 0; i < 8; ++i) s[i] = f2{0.f, 0.f};
  if (tid == 0) s[0].x = 1.f;

  for (int c = 0; c < NC; ++c) {
    const float4* M1 = &m1s[c * NQ];
    const float4* VF = &v1s[c * 10];
    if (c == 0) { // e0: 1q(q0), reg b0 (junction handles c=1,2)
      const float4 U = M1[0];
#pragma unroll
      for (int r = 0; r < 8; r += 2) apply2p(s[r], s[r + 1], U);
    }
    { // e1: F(1|0): target q1 (lane b5, permlane32), ctrl q0 = reg b0 (per-amp U)
      const bool hi = (lane & 32) != 0;
#pragma unroll
      for (int r = 0; r < 8; ++r)
        gpartp(s[r], plp32_2(s[r], lane), (r & 1) ? VF[0] : M1[1], hi);
    }
    { // e2: F(2|1): target q2 (lane b4, permlane16), ctrl q1 (lane b5)
      const float4 U = *((lane & 32) ? &VF[1] : &M1[2]);
      const bool hi = (lane & 16) != 0;
#pragma unroll
      for (int r = 0; r < 8; ++r) gpartp(s[r], plp16_2(s[r], lane), U, hi);
    }
    { // e3: F(3|2): target q3 (lane b3, xor8), ctrl q2 (lane b4)
      const float4 U = *((lane & 16) ? &VF[2] : &M1[3]);
      const bool hi = (lane & 8) != 0;
#pragma unroll
      for (int r = 0; r < 8; ++r) gpartp(s[r], swz2<0x201F>(s[r]), U, hi);
    }
    { // e4: F(4|3): target q4 (lane b2, xor4), ctrl q3 (lane b3)
      const float4 U = *((lane & 8) ? &VF[3] : &M1[4]);
      const bool hi = (lane & 4) != 0;
#pragma unroll
      for (int r = 0; r < 8; ++r) gpartp(s[r], swz2<0x101F>(s[r]), U, hi);
    }
    // e5: F(5|4): target q5 (wave b1), ctrl q4 (lane b2)
    g_wave8<2>(s, *((lane & 4) ? &VF[4] : &M1[5]), ex0, wave, lane);
    // e6: F(6|5): target q6 (wave b0), ctrl q5 (wave b1)
    g_wave8<1>(s, *((wave & 2) ? &VF[5] : &M1[6]), ex1, wave, lane);
    { // e7: F(7|6): target q7 (lane b1, dpp xor2), ctrl q6 (wave b0)
      const float4 U = *((wave & 1) ? &VF[6] : &M1[7]);
      const bool hi = (lane & 2) != 0;
#pragma unroll
      for (int r = 0; r < 8; ++r) gpartp(s[r], dpp2<0x4E>(s[r]), U, hi);
    }
    { // e8: F(8|7): target q8 (lane b0, dpp xor1), ctrl q7 (lane b1)
      const float4 U = *((lane & 2) ? &VF[7] : &M1[8]);
      const bool hi = (lane & 1) != 0;
#pragma unroll
      for (int r = 0; r < 8; ++r) gpartp(s[r], dpp2<0xB1>(s[r]), U, hi);
    }
    { // e9: F(9|8): target q9 = reg b1, ctrl q8 = lane b0 (per-lane U)
      const float4 U = *((lane & 1) ? &VF[8] : &M1[9]);
      apply2p(s[0], s[2], U); apply2p(s[1], s[3], U);
      apply2p(s[4], s[6], U); apply2p(s[5], s[7], U);
    }
    { // e10: F(10|9): target q10 = reg b2, ctrl q9 = reg b1 (static)
      const float4 U0 = M1[10], U1 = VF[9];
      apply2p(s[0], s[4], U0); apply2p(s[1], s[5], U0);
      apply2p(s[2], s[6], U1); apply2p(s[3], s[7], U1);
    }
    if (c < 2) { // junction: 1q(q0)_{c+1} ∘ C(10->0)_c : target reg b0, U by reg b2
      const float4 Un = m1s[(c + 1) * NQ];
      const float4 Uj = js[c];
      apply2p(s[0], s[1], Un); apply2p(s[2], s[3], Un);
      apply2p(s[4], s[5], Uj); apply2p(s[6], s[7], Uj);
    } else {     // e11: C(10->0): ctrl reg b2, target reg b0 (static)
      const float4 U = m2s[c * NQ + 10];
      apply2p(s[4], s[5], U); apply2p(s[6], s[7], U);
    }
  }

  // ---- expectations ----
  const int base = (wave << 6) | lane;
#pragma unroll
  for (int i = 0; i < 8; ++i) ex0[(i << 8) | base] = s[i];
  __syncthreads();
  const int pb2 = ((wave ^ 2) << 6) | lane;
  const int pb1 = ((wave ^ 1) << 6) | lane;
  f2 aq5 = {0,0}, aq6 = {0,0};
#pragma unroll
  for (int i = 0; i < 8; ++i) {
    aq5 += s[i] * ex0[(i << 8) | pb2];
    aq6 += s[i] * ex0[(i << 8) | pb1];
  }
  f2 zt = {0,0}, z0v = {0,0}, z9v = {0,0}, z10v = {0,0};
#pragma unroll
  for (int r = 0; r < 8; ++r) {
    const f2 m = s[r] * s[r];
    zt += m;
    z0v  += (r & 1) ? -m : m;
    z9v  += (r & 2) ? -m : m;
    z10v += (r & 4) ? -m : m;
  }
  f2 aq0 = {0,0}, aq9 = {0,0}, aq10 = {0,0};
#pragma unroll
  for (int r = 0; r < 8; ++r) {
    aq0  += s[r] * s[r ^ 1];
    aq9  += s[r] * s[r ^ 2];
    aq10 += s[r] * s[r ^ 4];
  }
  f2 aq1={0,0}, aq2={0,0}, aq3={0,0}, aq4={0,0}, aq7={0,0}, aq8={0,0};
#pragma unroll
  for (int r = 0; r < 8; ++r) {
    aq1 += s[r] * plp32_2(s[r], lane);
    aq2 += s[r] * plp16_2(s[r], lane);
    aq3 += s[r] * swz2<0x201F>(s[r]);
    aq4 += s[r] * swz2<0x101F>(s[r]);
    aq7 += s[r] * dpp2<0x4E>(s[r]);
    aq8 += s[r] * dpp2<0xB1>(s[r]);
  }
  const float ztot = zt.x + zt.y;

  float v[22];
  v[0]=aq0.x+aq0.y; v[1]=aq1.x+aq1.y; v[2]=aq2.x+aq2.y; v[3]=aq3.x+aq3.y;
  v[4]=aq4.x+aq4.y; v[5]=aq5.x+aq5.y; v[6]=aq6.x+aq6.y;
  v[7]=aq7.x+aq7.y; v[8]=aq8.x+aq8.y; v[9]=aq9.x+aq9.y; v[10]=aq10.x+aq10.y;
  v[11] = z0v.x + z0v.y;                // Z q0
  v[12] = (lane & 32) ? -ztot : ztot;   // Z q1
  v[13] = (lane & 16) ? -ztot : ztot;   // Z q2
  v[14] = (lane & 8)  ? -ztot : ztot;   // Z q3
  v[15] = (lane & 4)  ? -ztot : ztot;   // Z q4
  v[16] = (wave & 2)  ? -ztot : ztot;   // Z q5
  v[17] = (wave & 1)  ? -ztot : ztot;   // Z q6
  v[18] = (lane & 2)  ? -ztot : ztot;   // Z q7
  v[19] = (lane & 1)  ? -ztot : ztot;   // Z q8
  v[20] = z9v.x + z9v.y;                // Z q9
  v[21] = z10v.x + z10v.y;              // Z q10

  // reduction: DPP quad levels, pack 4/reg, ds_swizzle xor4/8, permlane 16/32
#pragma unroll
  for (int k = 0; k < 22; ++k) {
    v[k] += dppx<0xB1>(v[k]);
    v[k] += dppx<0x4E>(v[k]);
  }
  const int q4l = lane & 3;
  float wv[6];
#pragma unroll
  for (int p = 0; p < 5; ++p)
    wv[p] = q4l == 0 ? v[4*p] : (q4l == 1 ? v[4*p+1] : (q4l == 2 ? v[4*p+2] : v[4*p+3]));
  wv[5] = q4l == 0 ? v[20] : (q4l == 1 ? v[21] : 0.f);
#pragma unroll
  for (int p = 0; p < 6; ++p) {
    wv[p] += swz1<0x101F>(wv[p]);
    wv[p] += swz1<0x201F>(wv[p]);
    wv[p] = plsum16(wv[p]);
    wv[p] = plsum32(wv[p]);
  }
  if (lane < 4) {
#pragma unroll
    for (int p = 0; p < 6; ++p) red[wave][4*p + lane] = wv[p];
  }
  __syncthreads();
  if (tid < 22) {
    float sacc = 0.f;
#pragma unroll
    for (int w4 = 0; w4 < 4; ++w4) sacc += red[w4][tid];
    out[bidx * 22 + tid] = sacc;
  }
}

extern "C" void kernel_launch(void* const* d_in, const int* in_sizes, int n_in,
                              void* d_out, int out_size, void* d_ws, size_t ws_size,
                              hipStream_t stream) {
  (void)n_in; (void)d_ws; (void)ws_size; (void)out_size;
  const float* x = (const float*)d_in[0];
  const float* W = (const float*)d_in[1];
  const float* b = (const float*)d_in[2];
  float* out = (float*)d_out;
  const int batch = in_sizes[0] / NQ;
  qsim_kernel<<<batch, BLOCK, 0, stream>>>(x, W, b, out);
}

// Round 17
// 19.897 us; speedup vs baseline: 1.3990x; 1.0260x over previous
//
#include <hip/hip_runtime.h>

#define NQ 11
#define NC 3
#define BLOCK 256

typedef float f2 __attribute__((ext_vector_type(2)));

__device__ __forceinline__ f2 swp(f2 v) { return __builtin_shufflevector(v, v, 1, 0); }

// DPP quad_perm: 0xB1 = xor1, 0x4E = xor2
template<int CTRL>
__device__ __forceinline__ float dppx(float v) {
  return __int_as_float(__builtin_amdgcn_update_dpp(
      0, __float_as_int(v), CTRL, 0xF, 0xF, false));
}
template<int CTRL>
__device__ __forceinline__ f2 dpp2(f2 v) {
  f2 r; r.x = dppx<CTRL>(v.x); r.y = dppx<CTRL>(v.y); return r;
}
// ds_swizzle BitMode xor patterns: xor4 = 0x101F, xor8 = 0x201F
template<int OFF>
__device__ __forceinline__ float swz1(float v) {
  return __int_as_float(__builtin_amdgcn_ds_swizzle(__float_as_int(v), OFF));
}
template<int OFF>
__device__ __forceinline__ f2 swz2(f2 v) {
  f2 r; r.x = swz1<OFF>(v.x); r.y = swz1<OFF>(v.y); return r;
}
// gfx950 permlane swaps (VALU pipe)
__device__ __forceinline__ float plp16(float v, int lane) {
  auto r = __builtin_amdgcn_permlane16_swap(__float_as_int(v), __float_as_int(v), false, false);
  return __int_as_float((lane & 16) ? r[0] : r[1]);
}
__device__ __forceinline__ float plp32(float v, int lane) {
  auto r = __builtin_amdgcn_permlane32_swap(__float_as_int(v), __float_as_int(v), false, false);
  return __int_as_float((lane & 32) ? r[0] : r[1]);
}
__device__ __forceinline__ f2 plp16_2(f2 v, int lane) {
  f2 r; r.x = plp16(v.x, lane); r.y = plp16(v.y, lane); return r;
}
__device__ __forceinline__ f2 plp32_2(f2 v, int lane) {
  f2 r; r.x = plp32(v.x, lane); r.y = plp32(v.y, lane); return r;
}
__device__ __forceinline__ float plsum16(float v) {
  auto r = __builtin_amdgcn_permlane16_swap(__float_as_int(v), __float_as_int(v), false, false);
  return __int_as_float(r[0]) + __int_as_float(r[1]);
}
__device__ __forceinline__ float plsum32(float v) {
  auto r = __builtin_amdgcn_permlane32_swap(__float_as_int(v), __float_as_int(v), false, false);
  return __int_as_float(r[0]) + __int_as_float(r[1]);
}

// SU(2) U = [[a,b],[-conj(b),conj(a)]] as float4 (ar,ai,br,bi).
// In-thread pair apply: (v0,v1) <- U (v0,v1)
__device__ __forceinline__ void apply2p(f2& v0, f2& v1, float4 U) {
  const f2 ai2 = {-U.y, U.y};
  const f2 bi2 = {-U.w, U.w};
  const f2 w0 = swp(v0), w1 = swp(v1);
  const f2 n0 =  U.x * v0 + ai2 * w0 + U.z * v1 + bi2 * w1;
  const f2 n1 = -U.z * v0 + bi2 * w0 + U.x * v1 - ai2 * w1;
  v0 = n0; v1 = n1;
}
// own/partner row apply: v <- row(hi) of U applied to (own=v, partner=p)
__device__ __forceinline__ void gpartp(f2& v, f2 p, float4 U, bool hi) {
  const f2 ai2 = hi ? f2{U.y, -U.y} : f2{-U.y, U.y};
  const float br = hi ? -U.z : U.z;
  const f2 bi2 = {-U.w, U.w};
  v = U.x * v + ai2 * swp(v) + br * p + bi2 * swp(p);
}
// SU2 product A*B (B applied first)
__device__ __forceinline__ float4 su2mul(float4 A, float4 B) {
  return make_float4(
    (A.x*B.x - A.y*B.y) - (A.z*B.z + A.w*B.w),
    (A.x*B.y + A.y*B.x) - (A.w*B.z - A.z*B.w),
    (A.x*B.z - A.y*B.w) + (A.z*B.x + A.w*B.y),
    (A.x*B.w + A.y*B.z) + (A.w*B.x - A.z*B.y));
}
// wave-bit gate via LDS exchange (8 f2 per thread, 4 waves)
template<int WVX>
__device__ __forceinline__ void g_wave8(f2 (&s)[8], float4 U, f2* buf, int wave, int lane) {
  const int base = (wave << 6) | lane;
#pragma unroll
  for (int i = 0; i < 8; ++i) buf[(i << 8) | base] = s[i];
  __syncthreads();
  const int pbase = ((wave ^ WVX) << 6) | lane;
  const bool hi = (wave & WVX) != 0;
#pragma unroll
  for (int i = 0; i < 8; ++i) gpartp(s[i], buf[(i << 8) | pbase], U, hi);
}

__global__ __launch_bounds__(BLOCK) void qsim_kernel(
    const float* __restrict__ x, const float* __restrict__ W,
    const float* __restrict__ bias, float* __restrict__ out) {
  const int bidx = blockIdx.x;
  const int tid = threadIdx.x;
  const int lane = tid & 63, wave = tid >> 6;   // wave 0..3

  __shared__ float4 m1s[NC * NQ];   // fused 1q matrices (SU2)
  __shared__ float4 m2s[NC * NQ];   // fused controlled matrices (SU2)
  __shared__ float4 v1s[NC * 10];   // V[t] = m2[t-1] * m1[t], t=1..10
  __shared__ float4 js[2];          // J[c] = m1[c+1][0] * m2[c][10]
  __shared__ f2 ex0[2048];
  __shared__ f2 ex1[2048];
  __shared__ float red[4][24];

  // x row: wave-uniform index -> scalar loads, no LDS stage, no barrier
  float xr[NQ];
#pragma unroll
  for (int i = 0; i < NQ; ++i) xr[i] = x[bidx * NQ + i];

  // ---- matrices: 66 threads, each computes its OWN angles (no angle stage) ----
  if (tid < 2 * NC * NQ) {
    const int kind = tid / (NC * NQ);
    const int id = tid - kind * (NC * NQ);
    const int c = id / NQ, q = id - c * NQ;
    if (kind == 0) {
      // angles rot 0..3 for (c,q)
      float a0 = bias[c*66 + q],      a1 = bias[c*66 + 11 + q];
      float a2 = bias[c*66 + 22 + q], a3 = bias[c*66 + 33 + q];
      const float* w0 = W + (c*66 + q) * NQ;
      const float* w1 = W + (c*66 + 11 + q) * NQ;
      const float* w2 = W + (c*66 + 22 + q) * NQ;
      const float* w3 = W + (c*66 + 33 + q) * NQ;
#pragma unroll
      for (int i = 0; i < NQ; ++i) {
        a0 += w0[i] * xr[i]; a1 += w1[i] * xr[i];
        a2 += w2[i] * xr[i]; a3 += w3[i] * xr[i];
      }
      // U = RZ(a3) RY(a2) RZ(a1) RY(a0), SU2 form (a,b)
      float s0,c0,s1,c1,s2,c2,s3,c3;
      sincosf(0.5f*a0, &s0,&c0);
      sincosf(0.5f*a1, &s1,&c1);
      sincosf(0.5f*a2, &s2,&c2);
      sincosf(0.5f*a3, &s3,&c3);
      const float mar = c1*c0, mai = -s1*c0;
      const float mbr = -c1*s0, mbi = s1*s0;
      const float nar = c2*mar + s2*mbr, nai = c2*mai - s2*mbi;
      const float nbr = c2*mbr - s2*mar, nbi = c2*mbi + s2*mai;
      m1s[id] = make_float4(c3*nar + s3*nai, c3*nai - s3*nar,
                            c3*nbr + s3*nbi, c3*nbi - s3*nbr);
    } else {
      // angles rot 4,5 for (c,q); U = RZ(a5) RY(a4)
      float a4 = bias[c*66 + 44 + q], a5 = bias[c*66 + 55 + q];
      const float* w4 = W + (c*66 + 44 + q) * NQ;
      const float* w5 = W + (c*66 + 55 + q) * NQ;
#pragma unroll
      for (int i = 0; i < NQ; ++i) {
        a4 += w4[i] * xr[i]; a5 += w5[i] * xr[i];
      }
      float s4,c4,s5,c5;
      sincosf(0.5f*a4, &s4,&c4);
      sincosf(0.5f*a5, &s5,&c5);
      m2s[id] = make_float4(c5*c4, -s5*c4, -c5*s4, s5*s4);
    }
  }
  __syncthreads();

  // V[c][t] = m2[c][t-1] * m1[c][t]; J[c] = m1[c+1][0] * m2[c][10]
  if (tid < NC * 10) {
    const int c = tid / 10, tt = tid - c * 10, t = tt + 1;
    v1s[tid] = su2mul(m2s[c*NQ + t - 1], m1s[c*NQ + t]);
  } else if (tid < NC * 10 + 2) {
    const int cc = tid - NC * 10;   // 0,1
    js[cc] = su2mul(m1s[(cc + 1) * NQ], m2s[cc * NQ + 10]);
  }
  __syncthreads();

  // amp bits: [2:0]=reg (b0<->q0, b1<->q9, b2<->q10);
  // [8:3]=lane bits 0..5 <-> q8,q7,q4,q3,q2,q1 ; [10:9]=wave bits 0..1 <-> q6,q5
  f2 s[8];
#pragma unroll
  for (int i = 0; i < 8; ++i) s[i] = f2{0.f, 0.f};
  if (tid == 0) s[0].x = 1.f;

  for (int c = 0; c < NC; ++c) {
    const float4* M1 = &m1s[c * NQ];
    const float4* VF = &v1s[c * 10];
    if (c == 0) { // e0: 1q(q0), reg b0 (junction handles c=1,2)
      const float4 U = M1[0];
#pragma unroll
      for (int r = 0; r < 8; r += 2) apply2p(s[r], s[r + 1], U);
    }
    { // e1: F(1|0): target q1 (lane b5, permlane32), ctrl q0 = reg b0 (per-amp U)
      const bool hi = (lane & 32) != 0;
#pragma unroll
      for (int r = 0; r < 8; ++r)
        gpartp(s[r], plp32_2(s[r], lane), (r & 1) ? VF[0] : M1[1], hi);
    }
    { // e2: F(2|1): target q2 (lane b4, permlane16), ctrl q1 (lane b5)
      const float4 U = *((lane & 32) ? &VF[1] : &M1[2]);
      const bool hi = (lane & 16) != 0;
#pragma unroll
      for (int r = 0; r < 8; ++r) gpartp(s[r], plp16_2(s[r], lane), U, hi);
    }
    { // e3: F(3|2): target q3 (lane b3, xor8), ctrl q2 (lane b4)
      const float4 U = *((lane & 16) ? &VF[2] : &M1[3]);
      const bool hi = (lane & 8) != 0;
#pragma unroll
      for (int r = 0; r < 8; ++r) gpartp(s[r], swz2<0x201F>(s[r]), U, hi);
    }
    { // e4: F(4|3): target q4 (lane b2, xor4), ctrl q3 (lane b3)
      const float4 U = *((lane & 8) ? &VF[3] : &M1[4]);
      const bool hi = (lane & 4) != 0;
#pragma unroll
      for (int r = 0; r < 8; ++r) gpartp(s[r], swz2<0x101F>(s[r]), U, hi);
    }
    // e5: F(5|4): target q5 (wave b1), ctrl q4 (lane b2)
    g_wave8<2>(s, *((lane & 4) ? &VF[4] : &M1[5]), ex0, wave, lane);
    // e6: F(6|5): target q6 (wave b0), ctrl q5 (wave b1)
    g_wave8<1>(s, *((wave & 2) ? &VF[5] : &M1[6]), ex1, wave, lane);
    { // e7: F(7|6): target q7 (lane b1, dpp xor2), ctrl q6 (wave b0)
      const float4 U = *((wave & 1) ? &VF[6] : &M1[7]);
      const bool hi = (lane & 2) != 0;
#pragma unroll
      for (int r = 0; r < 8; ++r) gpartp(s[r], dpp2<0x4E>(s[r]), U, hi);
    }
    { // e8: F(8|7): target q8 (lane b0, dpp xor1), ctrl q7 (lane b1)
      const float4 U = *((lane & 2) ? &VF[7] : &M1[8]);
      const bool hi = (lane & 1) != 0;
#pragma unroll
      for (int r = 0; r < 8; ++r) gpartp(s[r], dpp2<0xB1>(s[r]), U, hi);
    }
    { // e9: F(9|8): target q9 = reg b1, ctrl q8 = lane b0 (per-lane U)
      const float4 U = *((lane & 1) ? &VF[8] : &M1[9]);
      apply2p(s[0], s[2], U); apply2p(s[1], s[3], U);
      apply2p(s[4], s[6], U); apply2p(s[5], s[7], U);
    }
    { // e10: F(10|9): target q10 = reg b2, ctrl q9 = reg b1 (static)
      const float4 U0 = M1[10], U1 = VF[9];
      apply2p(s[0], s[4], U0); apply2p(s[1], s[5], U0);
      apply2p(s[2], s[6], U1); apply2p(s[3], s[7], U1);
    }
    if (c < 2) { // junction: 1q(q0)_{c+1} ∘ C(10->0)_c : target reg b0, U by reg b2
      const float4 Un = m1s[(c + 1) * NQ];
      const float4 Uj = js[c];
      apply2p(s[0], s[1], Un); apply2p(s[2], s[3], Un);
      apply2p(s[4], s[5], Uj); apply2p(s[6], s[7], Uj);
    } else {     // e11: C(10->0): ctrl reg b2, target reg b0 (static)
      const float4 U = m2s[c * NQ + 10];
      apply2p(s[4], s[5], U); apply2p(s[6], s[7], U);
    }
  }

  // ---- expectations ----
  const int base = (wave << 6) | lane;
#pragma unroll
  for (int i = 0; i < 8; ++i) ex0[(i << 8) | base] = s[i];
  __syncthreads();
  const int pb2 = ((wave ^ 2) << 6) | lane;
  const int pb1 = ((wave ^ 1) << 6) | lane;
  f2 aq5 = {0,0}, aq6 = {0,0};
#pragma unroll
  for (int i = 0; i < 8; ++i) {
    aq5 += s[i] * ex0[(i << 8) | pb2];
    aq6 += s[i] * ex0[(i << 8) | pb1];
  }
  f2 zt = {0,0}, z0v = {0,0}, z9v = {0,0}, z10v = {0,0};
#pragma unroll
  for (int r = 0; r < 8; ++r) {
    const f2 m = s[r] * s[r];
    zt += m;
    z0v  += (r & 1) ? -m : m;
    z9v  += (r & 2) ? -m : m;
    z10v += (r & 4) ? -m : m;
  }
  f2 aq0 = {0,0}, aq9 = {0,0}, aq10 = {0,0};
#pragma unroll
  for (int r = 0; r < 8; ++r) {
    aq0  += s[r] * s[r ^ 1];
    aq9  += s[r] * s[r ^ 2];
    aq10 += s[r] * s[r ^ 4];
  }
  f2 aq1={0,0}, aq2={0,0}, aq3={0,0}, aq4={0,0}, aq7={0,0}, aq8={0,0};
#pragma unroll
  for (int r = 0; r < 8; ++r) {
    aq1 += s[r] * plp32_2(s[r], lane);
    aq2 += s[r] * plp16_2(s[r], lane);
    aq3 += s[r] * swz2<0x201F>(s[r]);
    aq4 += s[r] * swz2<0x101F>(s[r]);
    aq7 += s[r] * dpp2<0x4E>(s[r]);
    aq8 += s[r] * dpp2<0xB1>(s[r]);
  }
  const float ztot = zt.x + zt.y;

  float v[22];
  v[0]=aq0.x+aq0.y; v[1]=aq1.x+aq1.y; v[2]=aq2.x+aq2.y; v[3]=aq3.x+aq3.y;
  v[4]=aq4.x+aq4.y; v[5]=aq5.x+aq5.y; v[6]=aq6.x+aq6.y;
  v[7]=aq7.x+aq7.y; v[8]=aq8.x+aq8.y; v[9]=aq9.x+aq9.y; v[10]=aq10.x+aq10.y;
  v[11] = z0v.x + z0v.y;                // Z q0
  v[12] = (lane & 32) ? -ztot : ztot;   // Z q1
  v[13] = (lane & 16) ? -ztot : ztot;   // Z q2
  v[14] = (lane & 8)  ? -ztot : ztot;   // Z q3
  v[15] = (lane & 4)  ? -ztot : ztot;   // Z q4
  v[16] = (wave & 2)  ? -ztot : ztot;   // Z q5
  v[17] = (wave & 1)  ? -ztot : ztot;   // Z q6
  v[18] = (lane & 2)  ? -ztot : ztot;   // Z q7
  v[19] = (lane & 1)  ? -ztot : ztot;   // Z q8
  v[20] = z9v.x + z9v.y;                // Z q9
  v[21] = z10v.x + z10v.y;              // Z q10

  // reduction: DPP quad levels, pack 4/reg, ds_swizzle xor4/8, permlane 16/32
#pragma unroll
  for (int k = 0; k < 22; ++k) {
    v[k] += dppx<0xB1>(v[k]);
    v[k] += dppx<0x4E>(v[k]);
  }
  const int q4l = lane & 3;
  float wv[6];
#pragma unroll
  for (int p = 0; p < 5; ++p)
    wv[p] = q4l == 0 ? v[4*p] : (q4l == 1 ? v[4*p+1] : (q4l == 2 ? v[4*p+2] : v[4*p+3]));
  wv[5] = q4l == 0 ? v[20] : (q4l == 1 ? v[21] : 0.f);
#pragma unroll
  for (int p = 0; p < 6; ++p) {
    wv[p] += swz1<0x101F>(wv[p]);
    wv[p] += swz1<0x201F>(wv[p]);
    wv[p] = plsum16(wv[p]);
    wv[p] = plsum32(wv[p]);
  }
  if (lane < 4) {
#pragma unroll
    for (int p = 0; p < 6; ++p) red[wave][4*p + lane] = wv[p];
  }
  __syncthreads();
  if (tid < 22) {
    float sacc = 0.f;
#pragma unroll
    for (int w4 = 0; w4 < 4; ++w4) sacc += red[w4][tid];
    out[bidx * 22 + tid] = sacc;
  }
}

extern "C" void kernel_launch(void* const* d_in, const int* in_sizes, int n_in,
                              void* d_out, int out_size, void* d_ws, size_t ws_size,
                              hipStream_t stream) {
  (void)n_in; (void)d_ws; (void)ws_size; (void)out_size;
  const float* x = (const float*)d_in[0];
  const float* W = (const float*)d_in[1];
  const float* b = (const float*)d_in[2];
  float* out = (float*)d_out;
  const int batch = in_sizes[0] / NQ;
  qsim_kernel<<<batch, BLOCK, 0, stream>>>(x, W, b, out);
}